// Round 10
// baseline (503.510 us; speedup 1.0000x reference)
//
#include <hip/hip_runtime.h>
#include <hip/hip_bf16.h>

typedef __hip_bfloat16 bf16;
typedef __attribute__((ext_vector_type(8))) short short8;
typedef __attribute__((ext_vector_type(4))) float floatx4;

__device__ __forceinline__ float toF(bf16 v){ return __bfloat162float(v); }
__device__ __forceinline__ float b2f(unsigned short u){
  return __uint_as_float(((unsigned int)u) << 16);
}
__device__ __forceinline__ unsigned short f2bu(float f){
  bf16 h = __float2bfloat16(f);
  return *(unsigned short*)&h;
}
// load 8 consecutive fp32 and pack to 8 bf16 (one uint4)
__device__ __forceinline__ uint4 ld_cvt8(const float* p){
  float4 f0 = *(const float4*)p;
  float4 f1 = *(const float4*)(p + 4);
  unsigned short o[8] = {f2bu(f0.x), f2bu(f0.y), f2bu(f0.z), f2bu(f0.w),
                         f2bu(f1.x), f2bu(f1.y), f2bu(f1.z), f2bu(f1.w)};
  return *(const uint4*)o;
}

// ---------------------------------------------------------------------------
// Prep: LDS-tiled weight transposes (64x64, coalesced both sides) + srbase.
// (x cast eliminated: GEMMs read fp32 x directly.)
// ---------------------------------------------------------------------------
__global__ __launch_bounds__(256) void prep_all_kernel(
    const float* __restrict__ sr_w, const float* __restrict__ lepe_w,
    const float* __restrict__ kv2_w, const float* __restrict__ q1_w,
    const float* __restrict__ q2_w, const float* __restrict__ kv1_w,
    const float* __restrict__ proj_w,
    bf16* __restrict__ wT_sr, bf16* __restrict__ wT_x,
    bf16* __restrict__ wT_kv1, bf16* __restrict__ wT_proj,
    int* __restrict__ srbase) {
  const int tid = threadIdx.x;
  const int t = blockIdx.x;
  __shared__ float s[64][65];
  const float* src; bf16* dst; int K, N, kt, nt;
  if (t < 256)      { src = sr_w;   dst = wT_sr;          K = 4096; N = 256; kt = t >> 2;          nt = t & 3; }
  else if (t < 272) { src = lepe_w; dst = wT_x;           K = 256;  N = 256; kt = (t - 256) >> 2;  nt = (t - 256) & 3; }
  else if (t < 288) { src = kv2_w;  dst = wT_x + 65536;   K = 256;  N = 256; kt = (t - 272) >> 2;  nt = (t - 272) & 3; }
  else if (t < 296) { src = q1_w;   dst = wT_x + 131072;  K = 256;  N = 128; kt = (t - 288) >> 1;  nt = (t - 288) & 1; }
  else if (t < 304) { src = q2_w;   dst = wT_x + 163840;  K = 256;  N = 128; kt = (t - 296) >> 1;  nt = (t - 296) & 1; }
  else if (t < 320) { src = kv1_w;  dst = wT_kv1;         K = 256;  N = 256; kt = (t - 304) >> 2;  nt = (t - 304) & 3; }
  else if (t < 336) { src = proj_w; dst = wT_proj;        K = 256;  N = 256; kt = (t - 320) >> 2;  nt = (t - 320) & 3; }
  else {
    int tt = (t - 336) * 256 + tid;
    if (tt < 6272) {
      int b = tt / 196, p = tt - b * 196;
      int oy = p / 14, ox = p - oy * 14;
      srbase[tt] = ((b * 56 + oy * 4) * 56 + ox * 4) * 256;
    }
    return;
  }
  const int k0 = kt * 64, n0 = nt * 64;
#pragma unroll
  for (int p = tid; p < 4096; p += 256) {
    int k = p >> 6, n = p & 63;
    s[k][n] = src[(size_t)(k0 + k) * N + n0 + n];
  }
  __syncthreads();
#pragma unroll
  for (int p = tid; p < 4096; p += 256) {
    int n = p >> 6, k = p & 63;
    dst[(size_t)(n0 + n) * K + k0 + k] = __float2bfloat16(s[k][n]);
  }
}

// ---------------------------------------------------------------------------
// FUSED x3 + sr launch, reading fp32 x DIRECTLY (cast fused into staging).
// Blocks [0,392): srconv split-K/4 (K=1024 each, long blocks first).
// Blocks [392,5096): x3 (measured-best body, XCD-swizzled).
// ---------------------------------------------------------------------------
__global__ __launch_bounds__(256) void gemm_x3sr(
    const float* __restrict__ X, const bf16* __restrict__ BTx,
    const float* __restrict__ lepe_b,
    bf16* __restrict__ L1, bf16* __restrict__ KV2, bf16* __restrict__ Q12,
    const bf16* __restrict__ BTsr, const int* __restrict__ base,
    float* __restrict__ Cpart) {
  __shared__ uint4 As[128 * 5];
  __shared__ uint4 Bs[128 * 5];
  const int tid = threadIdx.x;
  const int wave = tid >> 6, lane = tid & 63;
  const int wm = (wave >> 1) * 64, wn = (wave & 1) * 64;
  const int l15 = lane & 15, quad = lane >> 4;
  floatx4 zero = {0.f, 0.f, 0.f, 0.f};
  floatx4 acc[4][4];
#pragma unroll
  for (int i = 0; i < 4; i++)
#pragma unroll
    for (int j = 0; j < 4; j++) acc[i][j] = zero;

  if (blockIdx.x < 392) {
    // ---------------- srconv split-K/4, fp32 gather + cast ----------------
    const int r = blockIdx.x;
    const int kz = r / 98, rem = r - kz * 98;
    const int m0 = (rem >> 1) * 128;
    const int n0 = (rem & 1) * 128;
    const int row0 = tid >> 2, row1 = 64 + (tid >> 2), seg = tid & 3;
    const int mb0 = base[m0 + row0];
    const int mb1 = base[m0 + row1];
    const bf16* bP0 = BTsr + (size_t)(n0 + row0) * 4096 + seg * 8;
    const bf16* bP1 = BTsr + (size_t)(n0 + row1) * 4096 + seg * 8;
    const int kbeg = kz * 1024;
    uint4 a0, a1, b0, b1;
    {
      int k = kbeg + seg * 8;
      int kp = k >> 8, c = k & 255;
      int off = ((kp >> 2) * 56 + (kp & 3)) * 256 + c;
      a0 = ld_cvt8(X + (size_t)mb0 + off);
      a1 = ld_cvt8(X + (size_t)mb1 + off);
      b0 = *(const uint4*)(bP0 + kbeg);
      b1 = *(const uint4*)(bP1 + kbeg);
    }
    for (int t = 0; t < 32; t++) {
      As[row0 * 5 + seg] = a0; As[row1 * 5 + seg] = a1;
      Bs[row0 * 5 + seg] = b0; Bs[row1 * 5 + seg] = b1;
      __syncthreads();
      if (t < 31) {
        int k = kbeg + (t + 1) * 32 + seg * 8;
        int kp = k >> 8, c = k & 255;
        int off = ((kp >> 2) * 56 + (kp & 3)) * 256 + c;
        a0 = ld_cvt8(X + (size_t)mb0 + off);
        a1 = ld_cvt8(X + (size_t)mb1 + off);
        b0 = *(const uint4*)(bP0 + kbeg + (t + 1) * 32);
        b1 = *(const uint4*)(bP1 + kbeg + (t + 1) * 32);
      }
      short8 af[4], bfr[4];
#pragma unroll
      for (int i = 0; i < 4; i++)
        af[i] = *(const short8*)&As[(wm + i * 16 + l15) * 5 + quad];
#pragma unroll
      for (int j = 0; j < 4; j++)
        bfr[j] = *(const short8*)&Bs[(wn + j * 16 + l15) * 5 + quad];
#pragma unroll
      for (int i = 0; i < 4; i++)
#pragma unroll
        for (int j = 0; j < 4; j++)
          acc[i][j] = __builtin_amdgcn_mfma_f32_16x16x32_bf16(bfr[j], af[i], acc[i][j], 0, 0, 0);
      __syncthreads();
    }
    float* Cp = Cpart + (size_t)kz * (6272 * 256);
#pragma unroll
    for (int i = 0; i < 4; i++) {
      int m = m0 + wm + i * 16 + l15;
#pragma unroll
      for (int j = 0; j < 4; j++) {
        int nb = n0 + wn + j * 16 + quad * 4;
        float4 o = {acc[i][j][0], acc[i][j][1], acc[i][j][2], acc[i][j][3]};
        *(float4*)&Cp[(size_t)m * 256 + nb] = o;
      }
    }
  } else {
    // ---------------- x3 (measured-best body, fp32 A + cast) ----------------
    const int bid = blockIdx.x - 392;
    const int sw = (bid & 7) * 588 + (bid >> 3);
    const int bx = sw % 6, by = sw / 6;
    const int m0 = by * 128;
    const int n0 = bx * 128;
    for (int k0 = 0; k0 < 256; k0 += 32) {
#pragma unroll
      for (int it = 0; it < 2; it++) {
        int id = it * 256 + tid;
        int row = id >> 2, seg = id & 3;
        As[row * 5 + seg] = ld_cvt8(X + (size_t)(m0 + row) * 256 + k0 + seg * 8);
        Bs[row * 5 + seg] = *(const uint4*)(BTx + (size_t)(n0 + row) * 256 + k0 + seg * 8);
      }
      __syncthreads();
      short8 af[4], bfr[4];
#pragma unroll
      for (int i = 0; i < 4; i++)
        af[i] = *(const short8*)&As[(wm + i * 16 + l15) * 5 + quad];
#pragma unroll
      for (int j = 0; j < 4; j++)
        bfr[j] = *(const short8*)&Bs[(wn + j * 16 + l15) * 5 + quad];
#pragma unroll
      for (int i = 0; i < 4; i++)
#pragma unroll
        for (int j = 0; j < 4; j++)
          acc[i][j] = __builtin_amdgcn_mfma_f32_16x16x32_bf16(af[i], bfr[j], acc[i][j], 0, 0, 0);
      __syncthreads();
    }
    const int segN = n0 >> 8;               // 0: lepe/L1, 1: KV2, 2: Q12
    bf16* Cd = (segN == 0) ? L1 : (segN == 1) ? KV2 : Q12;
    const int nc0 = n0 & 255;
#pragma unroll
    for (int j = 0; j < 4; j++) {
      int nl = nc0 + wn + j * 16 + l15;
      float bv = (segN == 0) ? lepe_b[nl] : 0.0f;
#pragma unroll
      for (int i = 0; i < 4; i++) {
        int m = m0 + wm + i * 16 + quad * 4;
#pragma unroll
        for (int r = 0; r < 4; r++)
          Cd[(size_t)(m + r) * 256 + nl] = __float2bfloat16(acc[i][j][r] + bv);
      }
    }
  }
}

// ---------------------------------------------------------------------------
// FUSED dwconv + ln_gelu. Blocks [0,12544): depthwise conv; [12544,18816):
// LayerNorm+GELU over 4 split-K partials + sr bias.
// ---------------------------------------------------------------------------
__global__ __launch_bounds__(256) void dwln_kernel(
    const bf16* __restrict__ L1in, const float* __restrict__ w,
    const float* __restrict__ cb,
    const float* __restrict__ part, const float* __restrict__ srb,
    const float* __restrict__ g, const float* __restrict__ bb,
    bf16* __restrict__ L2out, bf16* __restrict__ X1Nout) {
  const int tid = threadIdx.x;
  __shared__ float rs[4], rs2[4];
  if (blockIdx.x < 12544) {
    const int idx = blockIdx.x * 256 + tid;
    const int c8 = (idx & 31) * 8;
    const int sp = idx >> 5;
    const int xx = sp % 56;
    const int yb = sp / 56;
    const int yy = yb % 56;
    const int b  = yb / 56;
    float4 bb0 = *(const float4*)&cb[c8];
    float4 bb1 = *(const float4*)&cb[c8 + 4];
    float acc[8] = {bb0.x, bb0.y, bb0.z, bb0.w, bb1.x, bb1.y, bb1.z, bb1.w};
#pragma unroll
    for (int dy = 0; dy < 3; dy++) {
      int y = yy + dy - 1;
      if ((unsigned)y >= 56u) continue;
#pragma unroll
      for (int dx = 0; dx < 3; dx++) {
        int x = xx + dx - 1;
        if ((unsigned)x >= 56u) continue;
        uint4 v = *(const uint4*)&L1in[((size_t)((b * 56 + y) * 56 + x)) * 256 + c8];
        const unsigned short* pv = (const unsigned short*)&v;
        float4 w0 = *(const float4*)&w[(dy * 3 + dx) * 256 + c8];
        float4 w1 = *(const float4*)&w[(dy * 3 + dx) * 256 + c8 + 4];
        float wf[8] = {w0.x, w0.y, w0.z, w0.w, w1.x, w1.y, w1.z, w1.w};
#pragma unroll
        for (int e = 0; e < 8; e++) acc[e] += b2f(pv[e]) * wf[e];
      }
    }
    unsigned short o[8];
#pragma unroll
    for (int e = 0; e < 8; e++) o[e] = f2bu(acc[e]);
    *(uint4*)&L2out[(size_t)sp * 256 + c8] = *(const uint4*)o;
  } else {
    const int tok = blockIdx.x - 12544;
    float v = srb[tid];
    const float* p = part + (size_t)tok * 256 + tid;
#pragma unroll
    for (int c = 0; c < 4; c++) v += p[(size_t)c * 1605632];
    float s = v, s2 = v * v;
#pragma unroll
    for (int o = 32; o > 0; o >>= 1) {
      s += __shfl_down(s, o, 64);
      s2 += __shfl_down(s2, o, 64);
    }
    int wid = tid >> 6, lane = tid & 63;
    if (lane == 0) { rs[wid] = s; rs2[wid] = s2; }
    __syncthreads();
    float tot = rs[0] + rs[1] + rs[2] + rs[3];
    float tot2 = rs2[0] + rs2[1] + rs2[2] + rs2[3];
    float mean = tot * (1.0f / 256.0f);
    float var = tot2 * (1.0f / 256.0f) - mean * mean;
    float y = (v - mean) * rsqrtf(var + 1e-5f) * g[tid] + bb[tid];
    X1Nout[(size_t)tok * 256 + tid] =
        __float2bfloat16(0.5f * y * (1.0f + erff(y * 0.70710678118654752f)));
  }
}

// ---------------------------------------------------------------------------
// FUSED attn2 + kv1. Blocks [0,2048): window attention (win=bid&63, b=bid>>6).
// Blocks [2048,2146): kv1 GEMM. Shared memory union (54272 B).
// ---------------------------------------------------------------------------
__global__ __launch_bounds__(256) void attn2kv1_kernel(
    const bf16* __restrict__ Q12, const bf16* __restrict__ KV2,
    const bf16* __restrict__ X1N, const bf16* __restrict__ wT_kv1,
    bf16* __restrict__ X2, bf16* __restrict__ KV1) {
  __shared__ __align__(16) char smem[54272];
  const int tid = threadIdx.x;
  const int wave = tid >> 6, lane = tid & 63;
  const int l15 = lane & 15, quad = lane >> 4;
  floatx4 zero = {0.f, 0.f, 0.f, 0.f};

  if (blockIdx.x < 2048) {
    // ---------------- attn2 ----------------
    bf16* sk = (bf16*)smem;                 // [64][136]
    bf16* pbAll = (bf16*)(smem + 17408);    // [4][64*72]
    const int b = blockIdx.x >> 6;
    const int win = blockIdx.x & 63;
    const int wy = win >> 3, wx = win & 7;
    const int h = wave;

    for (int i = tid; i < 49 * 16; i += 256) {
      int m = i >> 4, c = i & 15;
      int iy = m / 7, ix = m - iy * 7;
      int n = (wy * 7 + iy) * 56 + wx * 7 + ix;
      *(uint4*)&sk[m * 136 + c * 8] =
          *(const uint4*)&KV2[((size_t)(b * 3136 + n)) * 256 + c * 8];
    }

    short8 bvv[2][2];
#pragma unroll
    for (int ks = 0; ks < 2; ks++)
#pragma unroll
      for (int nt = 0; nt < 2; nt++)
#pragma unroll
        for (int e = 0; e < 8; e++) {
          int k = ks * 32 + quad * 8 + e; if (k > 48) k = 48;
          int iy = k / 7, ix = k - iy * 7;
          int n = (wy * 7 + iy) * 56 + wx * 7 + ix;
          bvv[ks][nt][e] = ((const short*)KV2)[((size_t)(b * 3136 + n)) * 256
                                               + 128 + h * 32 + nt * 16 + l15];
        }

    short8 aq[4];
#pragma unroll
    for (int i = 0; i < 4; i++) {
      int lq = i * 16 + l15; if (lq > 48) lq = 48;
      int iy = lq / 7, ix = lq - iy * 7;
      int n = (wy * 7 + iy) * 56 + wx * 7 + ix;
      aq[i] = *(const short8*)(Q12 + ((size_t)(b * 3136 + n)) * 256 + 128 + h * 32 + quad * 8);
    }
    __syncthreads();

    const float scale = 0.17677669529663687f;
    floatx4 acc[4][2];
    float lsum[4][4];
#pragma unroll
    for (int i = 0; i < 4; i++) {
      acc[i][0] = zero; acc[i][1] = zero;
#pragma unroll
      for (int r = 0; r < 4; r++) lsum[i][r] = 0.f;
    }
    bf16* pw = pbAll + wave * (64 * 72);
#pragma unroll
    for (int c = 0; c < 2; c++) {
      const int kv0 = c * 32;
      short8 bk[2];
#pragma unroll
      for (int n = 0; n < 2; n++)
        bk[n] = *(const short8*)&sk[(kv0 + n * 16 + l15) * 136 + h * 32 + quad * 8];
      floatx4 s[4][2];
#pragma unroll
      for (int i = 0; i < 4; i++)
#pragma unroll
        for (int n = 0; n < 2; n++)
          s[i][n] = __builtin_amdgcn_mfma_f32_16x16x32_bf16(aq[i], bk[n], zero, 0, 0, 0);
#pragma unroll
      for (int i = 0; i < 4; i++)
#pragma unroll
        for (int n = 0; n < 2; n++) {
          bool valid = (kv0 + n * 16 + l15) < 49;
#pragma unroll
          for (int r = 0; r < 4; r++) {
            float p = valid ? __expf(s[i][n][r] * scale) : 0.f;
            lsum[i][r] += p;
            pw[(i * 16 + quad * 4 + r) * 72 + kv0 + n * 16 + l15] = __float2bfloat16(p);
          }
        }
    }
    asm volatile("s_waitcnt lgkmcnt(0)" ::: "memory");
#pragma unroll
    for (int ks = 0; ks < 2; ks++) {
      short8 ap[4];
#pragma unroll
      for (int i = 0; i < 4; i++)
        ap[i] = *(const short8*)&pw[(i * 16 + l15) * 72 + ks * 32 + quad * 8];
#pragma unroll
      for (int i = 0; i < 4; i++)
#pragma unroll
        for (int nt = 0; nt < 2; nt++)
          acc[i][nt] = __builtin_amdgcn_mfma_f32_16x16x32_bf16(ap[i], bvv[ks][nt], acc[i][nt], 0, 0, 0);
    }
#pragma unroll
    for (int i = 0; i < 4; i++)
#pragma unroll
      for (int r = 0; r < 4; r++) {
        float v = lsum[i][r];
        v += __shfl_xor(v, 1, 64);
        v += __shfl_xor(v, 2, 64);
        v += __shfl_xor(v, 4, 64);
        v += __shfl_xor(v, 8, 64);
        lsum[i][r] = 1.0f / v;
      }
#pragma unroll
    for (int i = 0; i < 4; i++)
#pragma unroll
      for (int r = 0; r < 4; r++) {
        int lq = i * 16 + quad * 4 + r;
        if (lq < 49) {
          int iy = lq / 7, ix = lq - iy * 7;
          int n = (wy * 7 + iy) * 56 + wx * 7 + ix;
          bf16* op = X2 + ((size_t)(b * 3136 + n)) * 128 + h * 32;
          op[l15]      = __float2bfloat16(acc[i][0][r] * lsum[i][r]);
          op[16 + l15] = __float2bfloat16(acc[i][1][r] * lsum[i][r]);
        }
      }
  } else {
    // ---------------- kv1 GEMM ----------------
    uint4* As = (uint4*)smem;
    uint4* Bs = (uint4*)(smem + 10240);
    const int r = blockIdx.x - 2048;
    const int m0 = (r >> 1) * 128;
    const int n0 = (r & 1) * 128;
    const int wm = (wave >> 1) * 64, wn = (wave & 1) * 64;
    const int row0 = tid >> 2, row1 = 64 + (tid >> 2), seg = tid & 3;
    const bf16* aP0 = X1N + (size_t)(m0 + row0) * 256 + seg * 8;
    const bf16* aP1 = X1N + (size_t)(m0 + row1) * 256 + seg * 8;
    const bf16* bP0 = wT_kv1 + (size_t)(n0 + row0) * 256 + seg * 8;
    const bf16* bP1 = wT_kv1 + (size_t)(n0 + row1) * 256 + seg * 8;
    floatx4 acc[4][4];
#pragma unroll
    for (int i = 0; i < 4; i++)
#pragma unroll
      for (int j = 0; j < 4; j++) acc[i][j] = zero;

    uint4 a0 = *(const uint4*)aP0, a1 = *(const uint4*)aP1;
    uint4 b0 = *(const uint4*)bP0, b1 = *(const uint4*)bP1;
#pragma unroll
    for (int t = 0; t < 8; t++) {
      As[row0 * 5 + seg] = a0; As[row1 * 5 + seg] = a1;
      Bs[row0 * 5 + seg] = b0; Bs[row1 * 5 + seg] = b1;
      __syncthreads();
      if (t < 7) {
        int k0 = (t + 1) * 32;
        a0 = *(const uint4*)(aP0 + k0); a1 = *(const uint4*)(aP1 + k0);
        b0 = *(const uint4*)(bP0 + k0); b1 = *(const uint4*)(bP1 + k0);
      }
      short8 af[4], bfr[4];
#pragma unroll
      for (int i = 0; i < 4; i++)
        af[i] = *(const short8*)&As[(wm + i * 16 + l15) * 5 + quad];
#pragma unroll
      for (int j = 0; j < 4; j++)
        bfr[j] = *(const short8*)&Bs[(wn + j * 16 + l15) * 5 + quad];
#pragma unroll
      for (int i = 0; i < 4; i++)
#pragma unroll
        for (int j = 0; j < 4; j++)
          acc[i][j] = __builtin_amdgcn_mfma_f32_16x16x32_bf16(bfr[j], af[i], acc[i][j], 0, 0, 0);
      __syncthreads();
    }
#pragma unroll
    for (int i = 0; i < 4; i++) {
      int m = m0 + wm + i * 16 + l15;
#pragma unroll
      for (int j = 0; j < 4; j++) {
        int nb = n0 + wn + j * 16 + quad * 4;
        ushort4 o;
        o.x = f2bu(acc[i][j][0]); o.y = f2bu(acc[i][j][1]);
        o.z = f2bu(acc[i][j][2]); o.w = f2bu(acc[i][j][3]);
        *(ushort4*)&KV1[(size_t)m * 256 + nb] = o;
      }
    }
  }
}

// ---------------------------------------------------------------------------
// attn1 (MFMA): per block 256 queries x one (b,h); kv = 196 (padded 224).
// ---------------------------------------------------------------------------
__global__ __launch_bounds__(256) void attn1_mfma(
    const bf16* __restrict__ Q12, const bf16* __restrict__ KV,
    bf16* __restrict__ O) {
  __shared__ bf16 sk[224 * 32];     // [kv][d]
  __shared__ bf16 svT[32 * 232];    // [d][kv], stride 232
  __shared__ bf16 pbuf[4][64 * 32]; // per-wave P [qrow][kv]
  const int b = blockIdx.z, h = blockIdx.y, chunk = blockIdx.x;
  const int tid = threadIdx.x;
  const int wave = tid >> 6, lane = tid & 63;
  const int l15 = lane & 15, quad = lane >> 4;
  for (int i = tid; i < 224 * 4; i += 256) {
    int m = i >> 2, c = i & 3;
    uint4 kv4 = {0u, 0u, 0u, 0u}, vv4 = {0u, 0u, 0u, 0u};
    if (m < 196) {
      const bf16* p = KV + ((size_t)(b * 196 + m)) * 256 + h * 32 + c * 8;
      kv4 = *(const uint4*)p;
      vv4 = *(const uint4*)(p + 128);
    }
    *(uint4*)&sk[m * 32 + c * 8] = kv4;
    const unsigned short* pv = (const unsigned short*)&vv4;
#pragma unroll
    for (int e = 0; e < 8; e++)
      *(unsigned short*)&svT[(c * 8 + e) * 232 + m] = pv[e];
  }
  __syncthreads();
  const int q0 = chunk * 256 + wave * 64;
  short8 aq[4];
#pragma unroll
  for (int i = 0; i < 4; i++) {
    int qr = q0 + i * 16 + l15; if (qr > 3135) qr = 3135;
    aq[i] = *(const short8*)(Q12 + ((size_t)(b * 3136 + qr)) * 256 + h * 32 + quad * 8);
  }
  const float scale = 0.17677669529663687f;
  floatx4 zero = {0.f, 0.f, 0.f, 0.f};
  floatx4 acc[4][2];
  float lsum[4][4];
#pragma unroll
  for (int i = 0; i < 4; i++) {
    acc[i][0] = zero; acc[i][1] = zero;
#pragma unroll
    for (int r = 0; r < 4; r++) lsum[i][r] = 0.f;
  }
  bf16* pw = pbuf[wave];
  for (int c = 0; c < 7; c++) {
    const int kv0 = c * 32;
    short8 bk[2];
#pragma unroll
    for (int n = 0; n < 2; n++)
      bk[n] = *(const short8*)&sk[(kv0 + n * 16 + l15) * 32 + quad * 8];
    floatx4 s[4][2];
#pragma unroll
    for (int i = 0; i < 4; i++)
#pragma unroll
      for (int n = 0; n < 2; n++)
        s[i][n] = __builtin_amdgcn_mfma_f32_16x16x32_bf16(aq[i], bk[n], zero, 0, 0, 0);
#pragma unroll
    for (int i = 0; i < 4; i++)
#pragma unroll
      for (int n = 0; n < 2; n++) {
        bool valid = (kv0 + n * 16 + l15) < 196;
#pragma unroll
        for (int r = 0; r < 4; r++) {
          float p = valid ? __expf(s[i][n][r] * scale) : 0.f;
          lsum[i][r] += p;
          pw[(i * 16 + quad * 4 + r) * 32 + n * 16 + l15] = __float2bfloat16(p);
        }
      }
    asm volatile("s_waitcnt lgkmcnt(0)" ::: "memory");
    short8 ap[4], bv[2];
#pragma unroll
    for (int i = 0; i < 4; i++)
      ap[i] = *(const short8*)&pw[(i * 16 + l15) * 32 + quad * 8];
#pragma unroll
    for (int n = 0; n < 2; n++)
      bv[n] = *(const short8*)&svT[(n * 16 + l15) * 232 + kv0 + quad * 8];
#pragma unroll
    for (int i = 0; i < 4; i++)
#pragma unroll
      for (int n = 0; n < 2; n++)
        acc[i][n] = __builtin_amdgcn_mfma_f32_16x16x32_bf16(ap[i], bv[n], acc[i][n], 0, 0, 0);
  }
#pragma unroll
  for (int i = 0; i < 4; i++)
#pragma unroll
    for (int r = 0; r < 4; r++) {
      float v = lsum[i][r];
      v += __shfl_xor(v, 1, 64);
      v += __shfl_xor(v, 2, 64);
      v += __shfl_xor(v, 4, 64);
      v += __shfl_xor(v, 8, 64);
      lsum[i][r] = 1.0f / v;
    }
#pragma unroll
  for (int i = 0; i < 4; i++)
#pragma unroll
    for (int r = 0; r < 4; r++) {
      int qr = q0 + i * 16 + quad * 4 + r;
      if (qr < 3136) {
        bf16* op = O + ((size_t)(b * 3136 + qr)) * 128 + h * 32;
        op[l15]      = __float2bfloat16(acc[i][0][r] * lsum[i][r]);
        op[16 + l15] = __float2bfloat16(acc[i][1][r] * lsum[i][r]);
      }
    }
}

// ---------------------------------------------------------------------------
// proj MFMA GEMM, fused A = concat(X1,X2)+L2, reg-staged pipeline.
// 1-D grid 1568, XCD-swizzled.
// ---------------------------------------------------------------------------
__global__ __launch_bounds__(256) void gemm_proj_mfma(
    const bf16* __restrict__ X1, const bf16* __restrict__ X2,
    const bf16* __restrict__ L2, const bf16* __restrict__ BT,
    const float* __restrict__ bias, float* __restrict__ C) {
  __shared__ uint4 As[128 * 5];
  __shared__ uint4 Bs[128 * 5];
  const int sw = (blockIdx.x & 7) * 196 + (blockIdx.x >> 3);
  const int tid = threadIdx.x;
  const int m0 = (sw >> 1) * 128;
  const int n0 = (sw & 1) * 128;
  const int wave = tid >> 6, lane = tid & 63;
  const int wm = (wave >> 1) * 64, wn = (wave & 1) * 64;
  const int l15 = lane & 15, quad = lane >> 4;
  const int row0 = tid >> 2, row1 = 64 + (tid >> 2), seg = tid & 3;
  const bf16* bP0 = BT + (size_t)(n0 + row0) * 256 + seg * 8;
  const bf16* bP1 = BT + (size_t)(n0 + row1) * 256 + seg * 8;
  floatx4 zero = {0.f, 0.f, 0.f, 0.f};
  floatx4 acc[4][4];
#pragma unroll
  for (int i = 0; i < 4; i++)
#pragma unroll
    for (int j = 0; j < 4; j++) acc[i][j] = zero;

  uint4 va0, va1, vl0, vl1, b0, b1;
  {
    int k = seg * 8;
    const bf16* s0 = X1 + (size_t)(m0 + row0) * 128 + k;   // k<128 at t=0
    const bf16* s1 = X1 + (size_t)(m0 + row1) * 128 + k;
    va0 = *(const uint4*)s0; va1 = *(const uint4*)s1;
    vl0 = *(const uint4*)(L2 + (size_t)(m0 + row0) * 256 + k);
    vl1 = *(const uint4*)(L2 + (size_t)(m0 + row1) * 256 + k);
    b0 = *(const uint4*)bP0; b1 = *(const uint4*)bP1;
  }
#pragma unroll
  for (int t = 0; t < 8; t++) {
    {
      unsigned short o0[8], o1[8];
      const unsigned short* pa0 = (const unsigned short*)&va0;
      const unsigned short* pl0 = (const unsigned short*)&vl0;
      const unsigned short* pa1 = (const unsigned short*)&va1;
      const unsigned short* pl1 = (const unsigned short*)&vl1;
#pragma unroll
      for (int e = 0; e < 8; e++) {
        o0[e] = f2bu(b2f(pa0[e]) + b2f(pl0[e]));
        o1[e] = f2bu(b2f(pa1[e]) + b2f(pl1[e]));
      }
      As[row0 * 5 + seg] = *(const uint4*)o0;
      As[row1 * 5 + seg] = *(const uint4*)o1;
      Bs[row0 * 5 + seg] = b0;
      Bs[row1 * 5 + seg] = b1;
    }
    __syncthreads();
    if (t < 7) {
      int k = (t + 1) * 32 + seg * 8;
      const bf16* s0 = (k < 128) ? X1 + (size_t)(m0 + row0) * 128 + k
                                 : X2 + (size_t)(m0 + row0) * 128 + (k - 128);
      const bf16* s1 = (k < 128) ? X1 + (size_t)(m0 + row1) * 128 + k
                                 : X2 + (size_t)(m0 + row1) * 128 + (k - 128);
      va0 = *(const uint4*)s0; va1 = *(const uint4*)s1;
      vl0 = *(const uint4*)(L2 + (size_t)(m0 + row0) * 256 + k);
      vl1 = *(const uint4*)(L2 + (size_t)(m0 + row1) * 256 + k);
      b0 = *(const uint4*)(bP0 + (t + 1) * 32);
      b1 = *(const uint4*)(bP1 + (t + 1) * 32);
    }
    short8 af[4], bfr[4];
#pragma unroll
    for (int i = 0; i < 4; i++)
      af[i] = *(const short8*)&As[(wm + i * 16 + l15) * 5 + quad];
#pragma unroll
    for (int j = 0; j < 4; j++)
      bfr[j] = *(const short8*)&Bs[(wn + j * 16 + l15) * 5 + quad];
#pragma unroll
    for (int i = 0; i < 4; i++)
#pragma unroll
      for (int j = 0; j < 4; j++)
        acc[i][j] = __builtin_amdgcn_mfma_f32_16x16x32_bf16(bfr[j], af[i], acc[i][j], 0, 0, 0);
    __syncthreads();
  }
#pragma unroll
  for (int i = 0; i < 4; i++) {
    int m = m0 + wm + i * 16 + l15;
#pragma unroll
    for (int j = 0; j < 4; j++) {
      int nb = n0 + wn + j * 16 + quad * 4;
      float4 bv = *(const float4*)&bias[nb];
      float4 o = {acc[i][j][0] + bv.x, acc[i][j][1] + bv.y,
                  acc[i][j][2] + bv.z, acc[i][j][3] + bv.w};
      *(float4*)&C[(size_t)m * 256 + nb] = o;
    }
  }
}

// ---------------------------------------------------------------------------
extern "C" void kernel_launch(void* const* d_in, const int* in_sizes, int n_in,
                              void* d_out, int out_size, void* d_ws, size_t ws_size,
                              hipStream_t stream) {
  const float* x           = (const float*)d_in[0];
  const float* lepe_lin_w  = (const float*)d_in[1];
  const float* lepe_lin_b  = (const float*)d_in[2];
  const float* lepe_conv_w = (const float*)d_in[3];
  const float* lepe_conv_b = (const float*)d_in[4];
  const float* sr_w        = (const float*)d_in[5];
  const float* sr_b        = (const float*)d_in[6];
  const float* norm_g      = (const float*)d_in[7];
  const float* norm_b      = (const float*)d_in[8];
  const float* q1_w        = (const float*)d_in[9];
  const float* kv1_w       = (const float*)d_in[10];
  const float* q2_w        = (const float*)d_in[11];
  const float* kv2_w       = (const float*)d_in[12];
  const float* proj_w      = (const float*)d_in[13];
  const float* proj_b      = (const float*)d_in[14];
  float* out = (float*)d_out;

  // Memory map (concurrency-safe for fused launches); x read directly (fp32).
  // d_out: X1N@0 (3.2M), KV1@8.4M (3.2M); Q12 [51.4,102.8M) dies after attn1;
  //        proj overwrites all of d_out last.
  // ws: [0,51.4M) L1 (x3 out, read by dwconv) -> X1 (attn1 out)
  //     [51.4,102.8M) L2 (dwconv out)
  //     [102.8,128.5M) X1Ppart (4 split-K fp32 partials) -> X2 (attn2 out)
  //     [128.5M..) weightsT, srbase, KV2.
  char* ws = (char*)d_ws;
  char* ob = (char*)d_out;
  const size_t szBNC = 100352ull * 256 * 2;   // 51,380,224
  const size_t szBNh = 100352ull * 128 * 2;   // 25,690,112
  bf16*  Q12 = (bf16*)(ob + szBNC);
  bf16*  L1  = (bf16*)ws;
  bf16*  X1  = (bf16*)ws;                     // after dwconv consumed L1
  bf16*  L2  = (bf16*)(ws + szBNC);
  float* X1Ppart = (float*)(ws + 2 * szBNC);  // 4 x 6,422,528 = 25,690,112
  bf16*  X2  = (bf16*)(ws + 2 * szBNC);       // after ln consumed partials
  bf16*  X1N = (bf16*)ob;                     // 3.2M
  bf16*  KV1 = (bf16*)(ob + 8388608);         // 3.2M bf16
  char*  wtb = ws + 2 * szBNC + szBNh;
  bf16* wT_x    = (bf16*)(wtb);               // [768,256]: lepe|kv2|q1|q2
  bf16* wT_kv1  = (bf16*)(wtb + 393216);
  bf16* wT_proj = (bf16*)(wtb + 524288);
  bf16* wT_sr   = (bf16*)(wtb + 655360);
  int*  srbase  = (int*)(wtb + 655360 + 2097152);
  bf16* KV2     = (bf16*)(wtb + 655360 + 2097152 + 32768);  // 51.4M

  // 0. weight transposes (LDS-tiled) + srbase (x cast eliminated)
  prep_all_kernel<<<361, 256, 0, stream>>>(
      sr_w, lepe_lin_w, kv2_w, q1_w, q2_w, kv1_w, proj_w,
      wT_sr, wT_x, wT_kv1, wT_proj, srbase);

  // 1. FUSED: srconv split-K/4 (392 long blocks first) + x3 projections,
  //    both reading fp32 x directly with fused cast
  gemm_x3sr<<<5096, 256, 0, stream>>>(
      x, wT_x, lepe_lin_b, L1, KV2, Q12, wT_sr, srbase, X1Ppart);

  // 2. FUSED: depthwise conv + LayerNorm/GELU partial-reduce
  dwln_kernel<<<18816, 256, 0, stream>>>(
      L1, lepe_conv_w, lepe_conv_b, X1Ppart, sr_b, norm_g, norm_b, L2, X1N);

  // 3. FUSED: window attention + kv1 GEMM
  attn2kv1_kernel<<<2146, 256, 0, stream>>>(Q12, KV2, X1N, wT_kv1, X2, KV1);

  // 4. branch-1 attention
  attn1_mfma<<<dim3(13, 4, 32), 256, 0, stream>>>(Q12, KV1, X1);

  // 5. fused concat + lepe add + proj
  gemm_proj_mfma<<<1568, 256, 0, stream>>>(
      X1, X2, L2, wT_proj, proj_b, out);
}

// Round 11
// 478.019 us; speedup vs baseline: 1.0533x; 1.0533x over previous
//
#include <hip/hip_runtime.h>
#include <hip/hip_bf16.h>

typedef __hip_bfloat16 bf16;
typedef __attribute__((ext_vector_type(8))) short short8;
typedef __attribute__((ext_vector_type(4))) float floatx4;

__device__ __forceinline__ float toF(bf16 v){ return __bfloat162float(v); }
__device__ __forceinline__ float b2f(unsigned short u){
  return __uint_as_float(((unsigned int)u) << 16);
}
__device__ __forceinline__ unsigned short f2bu(float f){
  bf16 h = __float2bfloat16(f);
  return *(unsigned short*)&h;
}

// ---------------------------------------------------------------------------
// Fused prep: x fp32->bf16 cast (blocks 0..25087) + LDS-tiled weight
// transposes (64x64 tiles, coalesced both sides) + srbase.
// ---------------------------------------------------------------------------
__global__ __launch_bounds__(256) void prep_all_kernel(
    const float* __restrict__ x, bf16* __restrict__ xb,
    const float* __restrict__ sr_w, const float* __restrict__ lepe_w,
    const float* __restrict__ kv2_w, const float* __restrict__ q1_w,
    const float* __restrict__ q2_w, const float* __restrict__ kv1_w,
    const float* __restrict__ proj_w,
    bf16* __restrict__ wT_sr, bf16* __restrict__ wT_x,
    bf16* __restrict__ wT_kv1, bf16* __restrict__ wT_proj,
    int* __restrict__ srbase) {
  const int tid = threadIdx.x;
  if (blockIdx.x < 25088) {
    size_t i4 = ((size_t)blockIdx.x * 256 + tid) * 4;
    float4 v = *(const float4*)(x + i4);
    ushort4 o;
    o.x = f2bu(v.x); o.y = f2bu(v.y); o.z = f2bu(v.z); o.w = f2bu(v.w);
    *(ushort4*)(xb + i4) = o;
    return;
  }
  const int t = blockIdx.x - 25088;
  __shared__ float s[64][65];
  const float* src; bf16* dst; int K, N, kt, nt;
  if (t < 256)      { src = sr_w;   dst = wT_sr;          K = 4096; N = 256; kt = t >> 2;          nt = t & 3; }
  else if (t < 272) { src = lepe_w; dst = wT_x;           K = 256;  N = 256; kt = (t - 256) >> 2;  nt = (t - 256) & 3; }
  else if (t < 288) { src = kv2_w;  dst = wT_x + 65536;   K = 256;  N = 256; kt = (t - 272) >> 2;  nt = (t - 272) & 3; }
  else if (t < 296) { src = q1_w;   dst = wT_x + 131072;  K = 256;  N = 128; kt = (t - 288) >> 1;  nt = (t - 288) & 1; }
  else if (t < 304) { src = q2_w;   dst = wT_x + 163840;  K = 256;  N = 128; kt = (t - 296) >> 1;  nt = (t - 296) & 1; }
  else if (t < 320) { src = kv1_w;  dst = wT_kv1;         K = 256;  N = 256; kt = (t - 304) >> 2;  nt = (t - 304) & 3; }
  else if (t < 336) { src = proj_w; dst = wT_proj;        K = 256;  N = 256; kt = (t - 320) >> 2;  nt = (t - 320) & 3; }
  else {
    int tt = (t - 336) * 256 + tid;
    if (tt < 6272) {
      int b = tt / 196, p = tt - b * 196;
      int oy = p / 14, ox = p - oy * 14;
      srbase[tt] = ((b * 56 + oy * 4) * 56 + ox * 4) * 256;
    }
    return;
  }
  const int k0 = kt * 64, n0 = nt * 64;
#pragma unroll
  for (int p = tid; p < 4096; p += 256) {
    int k = p >> 6, n = p & 63;
    s[k][n] = src[(size_t)(k0 + k) * N + n0 + n];
  }
  __syncthreads();
#pragma unroll
  for (int p = tid; p < 4096; p += 256) {
    int n = p >> 6, k = p & 63;
    dst[(size_t)(n0 + n) * K + k0 + k] = __float2bfloat16(s[k][n]);
  }
}

// ---------------------------------------------------------------------------
// FUSED x3 + sr launch. Blocks [0,392): srconv split-K/4 (K=1024 each, long
// blocks, dispatched first). Blocks [392,5096): x3 (measured-best body,
// XCD-swizzled). sr partials go to the X2 region (free until attn2).
// ---------------------------------------------------------------------------
__global__ __launch_bounds__(256) void gemm_x3sr(
    const bf16* __restrict__ A, const bf16* __restrict__ BTx,
    const float* __restrict__ lepe_b,
    bf16* __restrict__ L1, bf16* __restrict__ KV2, bf16* __restrict__ Q12,
    const bf16* __restrict__ BTsr, const int* __restrict__ base,
    float* __restrict__ Cpart) {
  __shared__ uint4 As[128 * 5];
  __shared__ uint4 Bs[128 * 5];
  const int tid = threadIdx.x;
  const int wave = tid >> 6, lane = tid & 63;
  const int wm = (wave >> 1) * 64, wn = (wave & 1) * 64;
  const int l15 = lane & 15, quad = lane >> 4;
  floatx4 zero = {0.f, 0.f, 0.f, 0.f};
  floatx4 acc[4][4];
#pragma unroll
  for (int i = 0; i < 4; i++)
#pragma unroll
    for (int j = 0; j < 4; j++) acc[i][j] = zero;

  if (blockIdx.x < 392) {
    // ---------------- srconv split-K/4 ----------------
    const int r = blockIdx.x;
    const int kz = r / 98, rem = r - kz * 98;
    const int m0 = (rem >> 1) * 128;
    const int n0 = (rem & 1) * 128;
    const int row0 = tid >> 2, row1 = 64 + (tid >> 2), seg = tid & 3;
    const int mb0 = base[m0 + row0];
    const int mb1 = base[m0 + row1];
    const bf16* bP0 = BTsr + (size_t)(n0 + row0) * 4096 + seg * 8;
    const bf16* bP1 = BTsr + (size_t)(n0 + row1) * 4096 + seg * 8;
    const int kbeg = kz * 1024;
    uint4 a0, a1, b0, b1;
    {
      int k = kbeg + seg * 8;
      int kp = k >> 8, c = k & 255;
      int off = ((kp >> 2) * 56 + (kp & 3)) * 256 + c;
      a0 = *(const uint4*)(A + (size_t)mb0 + off);
      a1 = *(const uint4*)(A + (size_t)mb1 + off);
      b0 = *(const uint4*)(bP0 + kbeg);
      b1 = *(const uint4*)(bP1 + kbeg);
    }
    for (int t = 0; t < 32; t++) {
      As[row0 * 5 + seg] = a0; As[row1 * 5 + seg] = a1;
      Bs[row0 * 5 + seg] = b0; Bs[row1 * 5 + seg] = b1;
      __syncthreads();
      if (t < 31) {
        int k = kbeg + (t + 1) * 32 + seg * 8;
        int kp = k >> 8, c = k & 255;
        int off = ((kp >> 2) * 56 + (kp & 3)) * 256 + c;
        a0 = *(const uint4*)(A + (size_t)mb0 + off);
        a1 = *(const uint4*)(A + (size_t)mb1 + off);
        b0 = *(const uint4*)(bP0 + kbeg + (t + 1) * 32);
        b1 = *(const uint4*)(bP1 + kbeg + (t + 1) * 32);
      }
      short8 af[4], bfr[4];
#pragma unroll
      for (int i = 0; i < 4; i++)
        af[i] = *(const short8*)&As[(wm + i * 16 + l15) * 5 + quad];
#pragma unroll
      for (int j = 0; j < 4; j++)
        bfr[j] = *(const short8*)&Bs[(wn + j * 16 + l15) * 5 + quad];
#pragma unroll
      for (int i = 0; i < 4; i++)
#pragma unroll
        for (int j = 0; j < 4; j++)
          acc[i][j] = __builtin_amdgcn_mfma_f32_16x16x32_bf16(bfr[j], af[i], acc[i][j], 0, 0, 0);
      __syncthreads();
    }
    float* Cp = Cpart + (size_t)kz * (6272 * 256);
#pragma unroll
    for (int i = 0; i < 4; i++) {
      int m = m0 + wm + i * 16 + l15;
#pragma unroll
      for (int j = 0; j < 4; j++) {
        int nb = n0 + wn + j * 16 + quad * 4;
        float4 o = {acc[i][j][0], acc[i][j][1], acc[i][j][2], acc[i][j][3]};
        *(float4*)&Cp[(size_t)m * 256 + nb] = o;
      }
    }
  } else {
    // ---------------- x3 (measured-best body) ----------------
    const int bid = blockIdx.x - 392;
    const int sw = (bid & 7) * 588 + (bid >> 3);
    const int bx = sw % 6, by = sw / 6;
    const int m0 = by * 128;
    const int n0 = bx * 128;
    for (int k0 = 0; k0 < 256; k0 += 32) {
#pragma unroll
      for (int it = 0; it < 2; it++) {
        int id = it * 256 + tid;
        int row = id >> 2, seg = id & 3;
        As[row * 5 + seg] = *(const uint4*)(A + (size_t)(m0 + row) * 256 + k0 + seg * 8);
        Bs[row * 5 + seg] = *(const uint4*)(BTx + (size_t)(n0 + row) * 256 + k0 + seg * 8);
      }
      __syncthreads();
      short8 af[4], bfr[4];
#pragma unroll
      for (int i = 0; i < 4; i++)
        af[i] = *(const short8*)&As[(wm + i * 16 + l15) * 5 + quad];
#pragma unroll
      for (int j = 0; j < 4; j++)
        bfr[j] = *(const short8*)&Bs[(wn + j * 16 + l15) * 5 + quad];
#pragma unroll
      for (int i = 0; i < 4; i++)
#pragma unroll
        for (int j = 0; j < 4; j++)
          acc[i][j] = __builtin_amdgcn_mfma_f32_16x16x32_bf16(af[i], bfr[j], acc[i][j], 0, 0, 0);
      __syncthreads();
    }
    const int segN = n0 >> 8;               // 0: lepe/L1, 1: KV2, 2: Q12
    bf16* Cd = (segN == 0) ? L1 : (segN == 1) ? KV2 : Q12;
    const int nc0 = n0 & 255;
#pragma unroll
    for (int j = 0; j < 4; j++) {
      int nl = nc0 + wn + j * 16 + l15;
      float bv = (segN == 0) ? lepe_b[nl] : 0.0f;
#pragma unroll
      for (int i = 0; i < 4; i++) {
        int m = m0 + wm + i * 16 + quad * 4;
#pragma unroll
        for (int r = 0; r < 4; r++)
          Cd[(size_t)(m + r) * 256 + nl] = __float2bfloat16(acc[i][j][r] + bv);
      }
    }
  }
}

// ---------------------------------------------------------------------------
// FUSED dwconv + ln_gelu. Blocks [0,12544): depthwise conv; [12544,18816):
// LayerNorm+GELU over 4 split-K partials + sr bias.
// ---------------------------------------------------------------------------
__global__ __launch_bounds__(256) void dwln_kernel(
    const bf16* __restrict__ L1in, const float* __restrict__ w,
    const float* __restrict__ cb,
    const float* __restrict__ part, const float* __restrict__ srb,
    const float* __restrict__ g, const float* __restrict__ bb,
    bf16* __restrict__ L2out, bf16* __restrict__ X1Nout) {
  const int tid = threadIdx.x;
  __shared__ float rs[4], rs2[4];
  if (blockIdx.x < 12544) {
    const int idx = blockIdx.x * 256 + tid;
    const int c8 = (idx & 31) * 8;
    const int sp = idx >> 5;
    const int xx = sp % 56;
    const int yb = sp / 56;
    const int yy = yb % 56;
    const int b  = yb / 56;
    float4 bb0 = *(const float4*)&cb[c8];
    float4 bb1 = *(const float4*)&cb[c8 + 4];
    float acc[8] = {bb0.x, bb0.y, bb0.z, bb0.w, bb1.x, bb1.y, bb1.z, bb1.w};
#pragma unroll
    for (int dy = 0; dy < 3; dy++) {
      int y = yy + dy - 1;
      if ((unsigned)y >= 56u) continue;
#pragma unroll
      for (int dx = 0; dx < 3; dx++) {
        int x = xx + dx - 1;
        if ((unsigned)x >= 56u) continue;
        uint4 v = *(const uint4*)&L1in[((size_t)((b * 56 + y) * 56 + x)) * 256 + c8];
        const unsigned short* pv = (const unsigned short*)&v;
        float4 w0 = *(const float4*)&w[(dy * 3 + dx) * 256 + c8];
        float4 w1 = *(const float4*)&w[(dy * 3 + dx) * 256 + c8 + 4];
        float wf[8] = {w0.x, w0.y, w0.z, w0.w, w1.x, w1.y, w1.z, w1.w};
#pragma unroll
        for (int e = 0; e < 8; e++) acc[e] += b2f(pv[e]) * wf[e];
      }
    }
    unsigned short o[8];
#pragma unroll
    for (int e = 0; e < 8; e++) o[e] = f2bu(acc[e]);
    *(uint4*)&L2out[(size_t)sp * 256 + c8] = *(const uint4*)o;
  } else {
    const int tok = blockIdx.x - 12544;
    float v = srb[tid];
    const float* p = part + (size_t)tok * 256 + tid;
#pragma unroll
    for (int c = 0; c < 4; c++) v += p[(size_t)c * 1605632];
    float s = v, s2 = v * v;
#pragma unroll
    for (int o = 32; o > 0; o >>= 1) {
      s += __shfl_down(s, o, 64);
      s2 += __shfl_down(s2, o, 64);
    }
    int wid = tid >> 6, lane = tid & 63;
    if (lane == 0) { rs[wid] = s; rs2[wid] = s2; }
    __syncthreads();
    float tot = rs[0] + rs[1] + rs[2] + rs[3];
    float tot2 = rs2[0] + rs2[1] + rs2[2] + rs2[3];
    float mean = tot * (1.0f / 256.0f);
    float var = tot2 * (1.0f / 256.0f) - mean * mean;
    float y = (v - mean) * rsqrtf(var + 1e-5f) * g[tid] + bb[tid];
    X1Nout[(size_t)tok * 256 + tid] =
        __float2bfloat16(0.5f * y * (1.0f + erff(y * 0.70710678118654752f)));
  }
}

// ---------------------------------------------------------------------------
// FUSED attn2 + kv1. Blocks [0,2048): window attention (win=bid&63, b=bid>>6).
// Blocks [2048,2146): kv1 GEMM. Shared memory union (54272 B).
// ---------------------------------------------------------------------------
__global__ __launch_bounds__(256) void attn2kv1_kernel(
    const bf16* __restrict__ Q12, const bf16* __restrict__ KV2,
    const bf16* __restrict__ X1N, const bf16* __restrict__ wT_kv1,
    bf16* __restrict__ X2, bf16* __restrict__ KV1) {
  __shared__ __align__(16) char smem[54272];
  const int tid = threadIdx.x;
  const int wave = tid >> 6, lane = tid & 63;
  const int l15 = lane & 15, quad = lane >> 4;
  floatx4 zero = {0.f, 0.f, 0.f, 0.f};

  if (blockIdx.x < 2048) {
    // ---------------- attn2 ----------------
    bf16* sk = (bf16*)smem;                 // [64][136]
    bf16* pbAll = (bf16*)(smem + 17408);    // [4][64*72]
    const int b = blockIdx.x >> 6;
    const int win = blockIdx.x & 63;
    const int wy = win >> 3, wx = win & 7;
    const int h = wave;

    for (int i = tid; i < 49 * 16; i += 256) {
      int m = i >> 4, c = i & 15;
      int iy = m / 7, ix = m - iy * 7;
      int n = (wy * 7 + iy) * 56 + wx * 7 + ix;
      *(uint4*)&sk[m * 136 + c * 8] =
          *(const uint4*)&KV2[((size_t)(b * 3136 + n)) * 256 + c * 8];
    }

    short8 bvv[2][2];
#pragma unroll
    for (int ks = 0; ks < 2; ks++)
#pragma unroll
      for (int nt = 0; nt < 2; nt++)
#pragma unroll
        for (int e = 0; e < 8; e++) {
          int k = ks * 32 + quad * 8 + e; if (k > 48) k = 48;
          int iy = k / 7, ix = k - iy * 7;
          int n = (wy * 7 + iy) * 56 + wx * 7 + ix;
          bvv[ks][nt][e] = ((const short*)KV2)[((size_t)(b * 3136 + n)) * 256
                                               + 128 + h * 32 + nt * 16 + l15];
        }

    short8 aq[4];
#pragma unroll
    for (int i = 0; i < 4; i++) {
      int lq = i * 16 + l15; if (lq > 48) lq = 48;
      int iy = lq / 7, ix = lq - iy * 7;
      int n = (wy * 7 + iy) * 56 + wx * 7 + ix;
      aq[i] = *(const short8*)(Q12 + ((size_t)(b * 3136 + n)) * 256 + 128 + h * 32 + quad * 8);
    }
    __syncthreads();

    const float scale = 0.17677669529663687f;
    floatx4 acc[4][2];
    float lsum[4][4];
#pragma unroll
    for (int i = 0; i < 4; i++) {
      acc[i][0] = zero; acc[i][1] = zero;
#pragma unroll
      for (int r = 0; r < 4; r++) lsum[i][r] = 0.f;
    }
    bf16* pw = pbAll + wave * (64 * 72);
#pragma unroll
    for (int c = 0; c < 2; c++) {
      const int kv0 = c * 32;
      short8 bk[2];
#pragma unroll
      for (int n = 0; n < 2; n++)
        bk[n] = *(const short8*)&sk[(kv0 + n * 16 + l15) * 136 + h * 32 + quad * 8];
      floatx4 s[4][2];
#pragma unroll
      for (int i = 0; i < 4; i++)
#pragma unroll
        for (int n = 0; n < 2; n++)
          s[i][n] = __builtin_amdgcn_mfma_f32_16x16x32_bf16(aq[i], bk[n], zero, 0, 0, 0);
#pragma unroll
      for (int i = 0; i < 4; i++)
#pragma unroll
        for (int n = 0; n < 2; n++) {
          bool valid = (kv0 + n * 16 + l15) < 49;
#pragma unroll
          for (int r = 0; r < 4; r++) {
            float p = valid ? __expf(s[i][n][r] * scale) : 0.f;
            lsum[i][r] += p;
            pw[(i * 16 + quad * 4 + r) * 72 + kv0 + n * 16 + l15] = __float2bfloat16(p);
          }
        }
    }
    asm volatile("s_waitcnt lgkmcnt(0)" ::: "memory");
#pragma unroll
    for (int ks = 0; ks < 2; ks++) {
      short8 ap[4];
#pragma unroll
      for (int i = 0; i < 4; i++)
        ap[i] = *(const short8*)&pw[(i * 16 + l15) * 72 + ks * 32 + quad * 8];
#pragma unroll
      for (int i = 0; i < 4; i++)
#pragma unroll
        for (int nt = 0; nt < 2; nt++)
          acc[i][nt] = __builtin_amdgcn_mfma_f32_16x16x32_bf16(ap[i], bvv[ks][nt], acc[i][nt], 0, 0, 0);
    }
#pragma unroll
    for (int i = 0; i < 4; i++)
#pragma unroll
      for (int r = 0; r < 4; r++) {
        float v = lsum[i][r];
        v += __shfl_xor(v, 1, 64);
        v += __shfl_xor(v, 2, 64);
        v += __shfl_xor(v, 4, 64);
        v += __shfl_xor(v, 8, 64);
        lsum[i][r] = 1.0f / v;
      }
#pragma unroll
    for (int i = 0; i < 4; i++)
#pragma unroll
      for (int r = 0; r < 4; r++) {
        int lq = i * 16 + quad * 4 + r;
        if (lq < 49) {
          int iy = lq / 7, ix = lq - iy * 7;
          int n = (wy * 7 + iy) * 56 + wx * 7 + ix;
          bf16* op = X2 + ((size_t)(b * 3136 + n)) * 128 + h * 32;
          op[l15]      = __float2bfloat16(acc[i][0][r] * lsum[i][r]);
          op[16 + l15] = __float2bfloat16(acc[i][1][r] * lsum[i][r]);
        }
      }
  } else {
    // ---------------- kv1 GEMM ----------------
    uint4* As = (uint4*)smem;
    uint4* Bs = (uint4*)(smem + 10240);
    const int r = blockIdx.x - 2048;
    const int m0 = (r >> 1) * 128;
    const int n0 = (r & 1) * 128;
    const int wm = (wave >> 1) * 64, wn = (wave & 1) * 64;
    const int row0 = tid >> 2, row1 = 64 + (tid >> 2), seg = tid & 3;
    const bf16* aP0 = X1N + (size_t)(m0 + row0) * 256 + seg * 8;
    const bf16* aP1 = X1N + (size_t)(m0 + row1) * 256 + seg * 8;
    const bf16* bP0 = wT_kv1 + (size_t)(n0 + row0) * 256 + seg * 8;
    const bf16* bP1 = wT_kv1 + (size_t)(n0 + row1) * 256 + seg * 8;
    floatx4 acc[4][4];
#pragma unroll
    for (int i = 0; i < 4; i++)
#pragma unroll
      for (int j = 0; j < 4; j++) acc[i][j] = zero;

    uint4 a0 = *(const uint4*)aP0, a1 = *(const uint4*)aP1;
    uint4 b0 = *(const uint4*)bP0, b1 = *(const uint4*)bP1;
#pragma unroll
    for (int t = 0; t < 8; t++) {
      As[row0 * 5 + seg] = a0; As[row1 * 5 + seg] = a1;
      Bs[row0 * 5 + seg] = b0; Bs[row1 * 5 + seg] = b1;
      __syncthreads();
      if (t < 7) {
        int k0 = (t + 1) * 32;
        a0 = *(const uint4*)(aP0 + k0); a1 = *(const uint4*)(aP1 + k0);
        b0 = *(const uint4*)(bP0 + k0); b1 = *(const uint4*)(bP1 + k0);
      }
      short8 af[4], bfr[4];
#pragma unroll
      for (int i = 0; i < 4; i++)
        af[i] = *(const short8*)&As[(wm + i * 16 + l15) * 5 + quad];
#pragma unroll
      for (int j = 0; j < 4; j++)
        bfr[j] = *(const short8*)&Bs[(wn + j * 16 + l15) * 5 + quad];
#pragma unroll
      for (int i = 0; i < 4; i++)
#pragma unroll
        for (int j = 0; j < 4; j++)
          acc[i][j] = __builtin_amdgcn_mfma_f32_16x16x32_bf16(bfr[j], af[i], acc[i][j], 0, 0, 0);
      __syncthreads();
    }
#pragma unroll
    for (int i = 0; i < 4; i++) {
      int m = m0 + wm + i * 16 + l15;
#pragma unroll
      for (int j = 0; j < 4; j++) {
        int nb = n0 + wn + j * 16 + quad * 4;
        ushort4 o;
        o.x = f2bu(acc[i][j][0]); o.y = f2bu(acc[i][j][1]);
        o.z = f2bu(acc[i][j][2]); o.w = f2bu(acc[i][j][3]);
        *(ushort4*)&KV1[(size_t)m * 256 + nb] = o;
      }
    }
  }
}

// ---------------------------------------------------------------------------
// attn1 (MFMA): per block 256 queries x one (b,h); kv = 196 (padded 224).
// ---------------------------------------------------------------------------
__global__ __launch_bounds__(256) void attn1_mfma(
    const bf16* __restrict__ Q12, const bf16* __restrict__ KV,
    bf16* __restrict__ O) {
  __shared__ bf16 sk[224 * 32];     // [kv][d]
  __shared__ bf16 svT[32 * 232];    // [d][kv], stride 232
  __shared__ bf16 pbuf[4][64 * 32]; // per-wave P [qrow][kv]
  const int b = blockIdx.z, h = blockIdx.y, chunk = blockIdx.x;
  const int tid = threadIdx.x;
  const int wave = tid >> 6, lane = tid & 63;
  const int l15 = lane & 15, quad = lane >> 4;
  for (int i = tid; i < 224 * 4; i += 256) {
    int m = i >> 2, c = i & 3;
    uint4 kv4 = {0u, 0u, 0u, 0u}, vv4 = {0u, 0u, 0u, 0u};
    if (m < 196) {
      const bf16* p = KV + ((size_t)(b * 196 + m)) * 256 + h * 32 + c * 8;
      kv4 = *(const uint4*)p;
      vv4 = *(const uint4*)(p + 128);
    }
    *(uint4*)&sk[m * 32 + c * 8] = kv4;
    const unsigned short* pv = (const unsigned short*)&vv4;
#pragma unroll
    for (int e = 0; e < 8; e++)
      *(unsigned short*)&svT[(c * 8 + e) * 232 + m] = pv[e];
  }
  __syncthreads();
  const int q0 = chunk * 256 + wave * 64;
  short8 aq[4];
#pragma unroll
  for (int i = 0; i < 4; i++) {
    int qr = q0 + i * 16 + l15; if (qr > 3135) qr = 3135;
    aq[i] = *(const short8*)(Q12 + ((size_t)(b * 3136 + qr)) * 256 + h * 32 + quad * 8);
  }
  const float scale = 0.17677669529663687f;
  floatx4 zero = {0.f, 0.f, 0.f, 0.f};
  floatx4 acc[4][2];
  float lsum[4][4];
#pragma unroll
  for (int i = 0; i < 4; i++) {
    acc[i][0] = zero; acc[i][1] = zero;
#pragma unroll
    for (int r = 0; r < 4; r++) lsum[i][r] = 0.f;
  }
  bf16* pw = pbuf[wave];
  for (int c = 0; c < 7; c++) {
    const int kv0 = c * 32;
    short8 bk[2];
#pragma unroll
    for (int n = 0; n < 2; n++)
      bk[n] = *(const short8*)&sk[(kv0 + n * 16 + l15) * 32 + quad * 8];
    floatx4 s[4][2];
#pragma unroll
    for (int i = 0; i < 4; i++)
#pragma unroll
      for (int n = 0; n < 2; n++)
        s[i][n] = __builtin_amdgcn_mfma_f32_16x16x32_bf16(aq[i], bk[n], zero, 0, 0, 0);
#pragma unroll
    for (int i = 0; i < 4; i++)
#pragma unroll
      for (int n = 0; n < 2; n++) {
        bool valid = (kv0 + n * 16 + l15) < 196;
#pragma unroll
        for (int r = 0; r < 4; r++) {
          float p = valid ? __expf(s[i][n][r] * scale) : 0.f;
          lsum[i][r] += p;
          pw[(i * 16 + quad * 4 + r) * 32 + n * 16 + l15] = __float2bfloat16(p);
        }
      }
    asm volatile("s_waitcnt lgkmcnt(0)" ::: "memory");
    short8 ap[4], bv[2];
#pragma unroll
    for (int i = 0; i < 4; i++)
      ap[i] = *(const short8*)&pw[(i * 16 + l15) * 32 + quad * 8];
#pragma unroll
    for (int n = 0; n < 2; n++)
      bv[n] = *(const short8*)&svT[(n * 16 + l15) * 232 + kv0 + quad * 8];
#pragma unroll
    for (int i = 0; i < 4; i++)
#pragma unroll
      for (int n = 0; n < 2; n++)
        acc[i][n] = __builtin_amdgcn_mfma_f32_16x16x32_bf16(ap[i], bv[n], acc[i][n], 0, 0, 0);
  }
#pragma unroll
  for (int i = 0; i < 4; i++)
#pragma unroll
    for (int r = 0; r < 4; r++) {
      float v = lsum[i][r];
      v += __shfl_xor(v, 1, 64);
      v += __shfl_xor(v, 2, 64);
      v += __shfl_xor(v, 4, 64);
      v += __shfl_xor(v, 8, 64);
      lsum[i][r] = 1.0f / v;
    }
#pragma unroll
  for (int i = 0; i < 4; i++)
#pragma unroll
    for (int r = 0; r < 4; r++) {
      int qr = q0 + i * 16 + quad * 4 + r;
      if (qr < 3136) {
        bf16* op = O + ((size_t)(b * 3136 + qr)) * 128 + h * 32;
        op[l15]      = __float2bfloat16(acc[i][0][r] * lsum[i][r]);
        op[16 + l15] = __float2bfloat16(acc[i][1][r] * lsum[i][r]);
      }
    }
}

// ---------------------------------------------------------------------------
// proj MFMA GEMM, fused A = concat(X1,X2)+L2, reg-staged pipeline.
// 1-D grid 1568, XCD-swizzled.
// ---------------------------------------------------------------------------
__global__ __launch_bounds__(256) void gemm_proj_mfma(
    const bf16* __restrict__ X1, const bf16* __restrict__ X2,
    const bf16* __restrict__ L2, const bf16* __restrict__ BT,
    const float* __restrict__ bias, float* __restrict__ C) {
  __shared__ uint4 As[128 * 5];
  __shared__ uint4 Bs[128 * 5];
  const int sw = (blockIdx.x & 7) * 196 + (blockIdx.x >> 3);
  const int tid = threadIdx.x;
  const int m0 = (sw >> 1) * 128;
  const int n0 = (sw & 1) * 128;
  const int wave = tid >> 6, lane = tid & 63;
  const int wm = (wave >> 1) * 64, wn = (wave & 1) * 64;
  const int l15 = lane & 15, quad = lane >> 4;
  const int row0 = tid >> 2, row1 = 64 + (tid >> 2), seg = tid & 3;
  const bf16* bP0 = BT + (size_t)(n0 + row0) * 256 + seg * 8;
  const bf16* bP1 = BT + (size_t)(n0 + row1) * 256 + seg * 8;
  floatx4 zero = {0.f, 0.f, 0.f, 0.f};
  floatx4 acc[4][4];
#pragma unroll
  for (int i = 0; i < 4; i++)
#pragma unroll
    for (int j = 0; j < 4; j++) acc[i][j] = zero;

  uint4 va0, va1, vl0, vl1, b0, b1;
  {
    int k = seg * 8;
    const bf16* s0 = X1 + (size_t)(m0 + row0) * 128 + k;   // k<128 at t=0
    const bf16* s1 = X1 + (size_t)(m0 + row1) * 128 + k;
    va0 = *(const uint4*)s0; va1 = *(const uint4*)s1;
    vl0 = *(const uint4*)(L2 + (size_t)(m0 + row0) * 256 + k);
    vl1 = *(const uint4*)(L2 + (size_t)(m0 + row1) * 256 + k);
    b0 = *(const uint4*)bP0; b1 = *(const uint4*)bP1;
  }
#pragma unroll
  for (int t = 0; t < 8; t++) {
    {
      unsigned short o0[8], o1[8];
      const unsigned short* pa0 = (const unsigned short*)&va0;
      const unsigned short* pl0 = (const unsigned short*)&vl0;
      const unsigned short* pa1 = (const unsigned short*)&va1;
      const unsigned short* pl1 = (const unsigned short*)&vl1;
#pragma unroll
      for (int e = 0; e < 8; e++) {
        o0[e] = f2bu(b2f(pa0[e]) + b2f(pl0[e]));
        o1[e] = f2bu(b2f(pa1[e]) + b2f(pl1[e]));
      }
      As[row0 * 5 + seg] = *(const uint4*)o0;
      As[row1 * 5 + seg] = *(const uint4*)o1;
      Bs[row0 * 5 + seg] = b0;
      Bs[row1 * 5 + seg] = b1;
    }
    __syncthreads();
    if (t < 7) {
      int k = (t + 1) * 32 + seg * 8;
      const bf16* s0 = (k < 128) ? X1 + (size_t)(m0 + row0) * 128 + k
                                 : X2 + (size_t)(m0 + row0) * 128 + (k - 128);
      const bf16* s1 = (k < 128) ? X1 + (size_t)(m0 + row1) * 128 + k
                                 : X2 + (size_t)(m0 + row1) * 128 + (k - 128);
      va0 = *(const uint4*)s0; va1 = *(const uint4*)s1;
      vl0 = *(const uint4*)(L2 + (size_t)(m0 + row0) * 256 + k);
      vl1 = *(const uint4*)(L2 + (size_t)(m0 + row1) * 256 + k);
      b0 = *(const uint4*)(bP0 + (t + 1) * 32);
      b1 = *(const uint4*)(bP1 + (t + 1) * 32);
    }
    short8 af[4], bfr[4];
#pragma unroll
    for (int i = 0; i < 4; i++)
      af[i] = *(const short8*)&As[(wm + i * 16 + l15) * 5 + quad];
#pragma unroll
    for (int j = 0; j < 4; j++)
      bfr[j] = *(const short8*)&Bs[(wn + j * 16 + l15) * 5 + quad];
#pragma unroll
    for (int i = 0; i < 4; i++)
#pragma unroll
      for (int j = 0; j < 4; j++)
        acc[i][j] = __builtin_amdgcn_mfma_f32_16x16x32_bf16(bfr[j], af[i], acc[i][j], 0, 0, 0);
    __syncthreads();
  }
#pragma unroll
  for (int i = 0; i < 4; i++) {
    int m = m0 + wm + i * 16 + l15;
#pragma unroll
    for (int j = 0; j < 4; j++) {
      int nb = n0 + wn + j * 16 + quad * 4;
      float4 bv = *(const float4*)&bias[nb];
      float4 o = {acc[i][j][0] + bv.x, acc[i][j][1] + bv.y,
                  acc[i][j][2] + bv.z, acc[i][j][3] + bv.w};
      *(float4*)&C[(size_t)m * 256 + nb] = o;
    }
  }
}

// ---------------------------------------------------------------------------
extern "C" void kernel_launch(void* const* d_in, const int* in_sizes, int n_in,
                              void* d_out, int out_size, void* d_ws, size_t ws_size,
                              hipStream_t stream) {
  const float* x           = (const float*)d_in[0];
  const float* lepe_lin_w  = (const float*)d_in[1];
  const float* lepe_lin_b  = (const float*)d_in[2];
  const float* lepe_conv_w = (const float*)d_in[3];
  const float* lepe_conv_b = (const float*)d_in[4];
  const float* sr_w        = (const float*)d_in[5];
  const float* sr_b        = (const float*)d_in[6];
  const float* norm_g      = (const float*)d_in[7];
  const float* norm_b      = (const float*)d_in[8];
  const float* q1_w        = (const float*)d_in[9];
  const float* kv1_w       = (const float*)d_in[10];
  const float* q2_w        = (const float*)d_in[11];
  const float* kv2_w       = (const float*)d_in[12];
  const float* proj_w      = (const float*)d_in[13];
  const float* proj_b      = (const float*)d_in[14];
  float* out = (float*)d_out;

  // Memory map (concurrency-safe for fused launches):
  // d_out: xb [0,51.4M) dies after x3sr -> X1N@0, KV1@8.4M; Q12 [51.4,102.8M)
  //        dies after attn1; proj overwrites all of d_out last.
  // ws: [0,51.4M) L1 (x3 out, read by dwconv) -> X1 (attn1 out)
  //     [51.4,102.8M) L2 (dwconv out)
  //     [102.8,128.5M) X1Ppart (4 split-K fp32 partials) -> X2 (attn2 out)
  //     [128.5M..) weightsT, srbase, KV2.
  char* ws = (char*)d_ws;
  char* ob = (char*)d_out;
  const size_t szBNC = 100352ull * 256 * 2;   // 51,380,224
  const size_t szBNh = 100352ull * 128 * 2;   // 25,690,112
  bf16*  xb  = (bf16*)ob;
  bf16*  Q12 = (bf16*)(ob + szBNC);
  bf16*  L1  = (bf16*)ws;
  bf16*  X1  = (bf16*)ws;                     // after dwconv consumed L1
  bf16*  L2  = (bf16*)(ws + szBNC);
  float* X1Ppart = (float*)(ws + 2 * szBNC);  // 4 x 6,422,528 = 25,690,112
  bf16*  X2  = (bf16*)(ws + 2 * szBNC);       // after ln consumed partials
  bf16*  X1N = (bf16*)ob;                     // 3.2M, in dead xb region
  bf16*  KV1 = (bf16*)(ob + 8388608);         // 3.2M bf16, in dead xb region
  char*  wtb = ws + 2 * szBNC + szBNh;
  bf16* wT_x    = (bf16*)(wtb);               // [768,256]: lepe|kv2|q1|q2
  bf16* wT_kv1  = (bf16*)(wtb + 393216);
  bf16* wT_proj = (bf16*)(wtb + 524288);
  bf16* wT_sr   = (bf16*)(wtb + 655360);
  int*  srbase  = (int*)(wtb + 655360 + 2097152);
  bf16* KV2     = (bf16*)(wtb + 655360 + 2097152 + 32768);  // 51.4M

  // 0. x cast + all weight transposes (LDS-tiled) + srbase
  prep_all_kernel<<<25449, 256, 0, stream>>>(
      x, xb, sr_w, lepe_lin_w, kv2_w, q1_w, q2_w, kv1_w, proj_w,
      wT_sr, wT_x, wT_kv1, wT_proj, srbase);

  // 1. FUSED: srconv split-K/4 (392 long blocks first) + x3 projections
  gemm_x3sr<<<5096, 256, 0, stream>>>(
      xb, wT_x, lepe_lin_b, L1, KV2, Q12, wT_sr, srbase, X1Ppart);

  // 2. FUSED: depthwise conv + LayerNorm/GELU partial-reduce
  dwln_kernel<<<18816, 256, 0, stream>>>(
      L1, lepe_conv_w, lepe_conv_b, X1Ppart, sr_b, norm_g, norm_b, L2, X1N);

  // 3. FUSED: window attention + kv1 GEMM
  attn2kv1_kernel<<<2146, 256, 0, stream>>>(Q12, KV2, X1N, wT_kv1, X2, KV1);

  // 4. branch-1 attention
  attn1_mfma<<<dim3(13, 4, 32), 256, 0, stream>>>(Q12, KV1, X1);

  // 5. fused concat + lepe add + proj
  gemm_proj_mfma<<<1568, 256, 0, stream>>>(
      X1, X2, L2, wT_proj, proj_b, out);
}